// Round 4
// baseline (3691.876 us; speedup 1.0000x reference)
//
#include <hip/hip_runtime.h>
#include <hip/hip_bf16.h>
#include <cstdint>
#include <cstddef>

#define NTOK 2048
#define HID  2048
#define NINT 5632
#define NEXP 8

typedef __attribute__((ext_vector_type(8))) short short8;
typedef __attribute__((ext_vector_type(4))) float f32x4;
typedef __attribute__((ext_vector_type(4))) float fl4;

__device__ __forceinline__ unsigned short f2bf(float f) {
    union { float f; unsigned int u; } v; v.f = f;
    unsigned int r = (v.u + 0x7fffu + ((v.u >> 16) & 1u)) >> 16;
    return (unsigned short)r;
}

// pack 2 floats -> 2 bf16 in one u32 (compiler emits v_cvt_pk_bf16_f32, RNE)
__device__ __forceinline__ unsigned int pk2(float x, float y) {
    __hip_bfloat162 h = __float22bfloat162_rn(make_float2(x, y));
    union { __hip_bfloat162 h; unsigned int u; } c; c.h = h;
    return c.u;
}

// meta layout (ints): [0..7]=cnt, [8..15]=cursor, [16..24]=offs
__global__ void zero_kernel(float* __restrict__ out, int* __restrict__ meta) {
    int idx = blockIdx.x * blockDim.x + threadIdx.x;   // 4096 x 256 fl4 = 16 MB
    fl4 z = {0.f, 0.f, 0.f, 0.f};
    ((fl4*)out)[idx] = z;
    if (blockIdx.x == 0 && threadIdx.x < 16) meta[threadIdx.x] = 0;
}

__device__ __forceinline__ void top2_route(const float* __restrict__ lg, int t,
                                           int& e0, int& e1, float& w0, float& w1) {
    float l[NEXP];
#pragma unroll
    for (int e = 0; e < NEXP; ++e) l[e] = lg[t * NEXP + e];
    e0 = 0; float b0l = l[0];
#pragma unroll
    for (int e = 1; e < NEXP; ++e) if (l[e] > b0l) { b0l = l[e]; e0 = e; }
    e1 = (e0 == 0) ? 1 : 0; float b1l = l[e1];
#pragma unroll
    for (int e = 0; e < NEXP; ++e) {
        if (e == e0) continue;
        if (l[e] > b1l) { b1l = l[e]; e1 = e; }
    }
    float m = b0l;
    float p0 = __expf(b0l - m), p1 = __expf(b1l - m);
    float inv = 1.f / (p0 + p1);
    w0 = p0 * inv; w1 = p1 * inv;
}

__global__ void route_count(const float* __restrict__ logits, int* __restrict__ meta) {
    int t = blockIdx.x * blockDim.x + threadIdx.x;
    int e0, e1; float w0, w1;
    top2_route(logits, t, e0, e1, w0, w1);
    atomicAdd(&meta[e0], 1);
    atomicAdd(&meta[e1], 1);
}

__global__ void scan_kernel(int* __restrict__ meta) {
    if (threadIdx.x == 0 && blockIdx.x == 0) {
        int s = 0;
#pragma unroll
        for (int e = 0; e < NEXP; ++e) { meta[16 + e] = s; s += meta[e]; }
        meta[16 + NEXP] = s;
    }
}

__global__ void route_assign(const float* __restrict__ logits, int* __restrict__ meta,
                             int* __restrict__ rowTok, float* __restrict__ rowW) {
    int t = blockIdx.x * blockDim.x + threadIdx.x;
    int e0, e1; float w0, w1;
    top2_route(logits, t, e0, e1, w0, w1);
    int p0 = atomicAdd(&meta[8 + e0], 1);
    int s0 = meta[16 + e0] + p0;
    rowTok[s0] = t; rowW[s0] = w0;
    int p1 = atomicAdd(&meta[8 + e1], 1);
    int s1 = meta[16 + e1] + p1;
    rowTok[s1] = t; rowW[s1] = w1;
}

__global__ void gather_x(const float* __restrict__ x, const int* __restrict__ rowTok,
                         unsigned short* __restrict__ xg) {
    int slot = blockIdx.x;
    int tok = rowTok[slot];
    int c = threadIdx.x;
    const fl4* src = (const fl4*)(x + (size_t)tok * HID);
    fl4 a = src[c * 2], b = src[c * 2 + 1];
    short8 v;
    v[0] = (short)f2bf(a[0]); v[1] = (short)f2bf(a[1]); v[2] = (short)f2bf(a[2]); v[3] = (short)f2bf(a[3]);
    v[4] = (short)f2bf(b[0]); v[5] = (short)f2bf(b[1]); v[6] = (short)f2bf(b[2]); v[7] = (short)f2bf(b[3]);
    *(short8*)(xg + (size_t)slot * HID + c * 8) = v;
}

// ---------------- GEMM1 ----------------
// Block: 256 thr (4 waves). Tile: 128 token-rows x 64 inter-cols.
// B (w1+w3, fp32) -> 2-step-deep reg prefetch -> cvt bf16 -> padded LDS dbuf.
// A (xg bf16) read per-wave directly from global (L2-hot). Raw s_barrier only
// (lgkmcnt(0), never vmcnt drain) so weight loads stay in flight 2 K-steps.
__global__ __launch_bounds__(256, 3) void gemm1_kernel(
        const unsigned short* __restrict__ xg,
        const float* __restrict__ w1, const float* __restrict__ w3,
        const int* __restrict__ meta, unsigned short* __restrict__ act) {
    const int ch = blockIdx.x;      // 16 chunks of 128 rows
    const int it = blockIdx.y;      // 88 tiles of 64 inter cols
    const int e  = blockIdx.z;      // 8 experts
    const int r0 = meta[16 + e];
    const int Ne = meta[17 + e] - r0;
    const int cb = ch * 128;
    if (cb >= Ne) return;

    __shared__ __align__(16) short Bs[2][128][72];

    const int tid = threadIdx.x;
    const int lane = tid & 63, w = tid >> 6;
    const int cl = lane & 15, kq = lane >> 4;
    const int rowb = cb + w * 32;

    // A pointers (clamped rows; duplicates masked at epilogue)
    int ra0 = rowb + cl;      if (ra0 > Ne - 1) ra0 = Ne - 1;
    int ra1 = rowb + 16 + cl; if (ra1 > Ne - 1) ra1 = Ne - 1;
    const unsigned short* a0p = xg + (size_t)(r0 + ra0) * HID + kq * 8;
    const unsigned short* a1p = xg + (size_t)(r0 + ra1) * HID + kq * 8;

    // B staging source: thread t stages LDS row tr (0..127), k-half th
    const int tr = tid >> 1;
    const int th = (tid & 1) * 32;
    const float* wrow;
    {
        const float* wbase = (tr < 64) ? w1 : w3;
        int wr = it * 64 + (tr & 63);
        wrow = wbase + ((size_t)e * NINT + wr) * HID + th;
    }

    f32x4 acc[2][8];
#pragma unroll
    for (int m = 0; m < 2; ++m)
#pragma unroll
        for (int f = 0; f < 8; ++f) acc[m][f] = (f32x4){0.f, 0.f, 0.f, 0.f};

    fl4 rb0[8], rb1[8];
    short8 aS[2][2];

#define G1_ISSUE_B(RB, K0) do { \
        _Pragma("unroll") for (int i_ = 0; i_ < 8; ++i_) \
            RB[i_] = *(const fl4*)(wrow + (K0) + i_ * 4); \
    } while (0)

#define G1_CVT_WRITE(RB, BUF) do { \
        _Pragma("unroll") for (int i_ = 0; i_ < 4; ++i_) { \
            union { short8 s; unsigned int u[4]; } vv_; \
            vv_.u[0] = pk2(RB[2*i_][0], RB[2*i_][1]); \
            vv_.u[1] = pk2(RB[2*i_][2], RB[2*i_][3]); \
            vv_.u[2] = pk2(RB[2*i_+1][0], RB[2*i_+1][1]); \
            vv_.u[3] = pk2(RB[2*i_+1][2], RB[2*i_+1][3]); \
            *(short8*)&Bs[BUF][tr][th + i_ * 8] = vv_.s; \
        } \
    } while (0)

#define G1_ISSUE_A(K0) do { \
        aS[0][0] = *(const short8*)(a0p + (K0)); \
        aS[0][1] = *(const short8*)(a0p + (K0) + 32); \
        aS[1][0] = *(const short8*)(a1p + (K0)); \
        aS[1][1] = *(const short8*)(a1p + (K0) + 32); \
    } while (0)

#define G1_COMPUTE(BUF) do { \
        _Pragma("unroll") for (int h_ = 0; h_ < 2; ++h_) { \
            _Pragma("unroll") for (int f_ = 0; f_ < 8; ++f_) { \
                short8 b_ = *(const short8*)&Bs[BUF][f_ * 16 + cl][h_ * 32 + kq * 8]; \
                acc[0][f_] = __builtin_amdgcn_mfma_f32_16x16x32_bf16(aS[0][h_], b_, acc[0][f_], 0, 0, 0); \
                acc[1][f_] = __builtin_amdgcn_mfma_f32_16x16x32_bf16(aS[1][h_], b_, acc[1][f_], 0, 0, 0); \
            } \
        } \
    } while (0)

#define LGKM_BAR() do { \
        asm volatile("s_waitcnt lgkmcnt(0)" ::: "memory"); \
        __builtin_amdgcn_s_barrier(); \
    } while (0)

    const int NS = HID / 64;   // 32 (even)
    G1_ISSUE_B(rb0, 0);
    G1_ISSUE_B(rb1, 64);
    G1_ISSUE_A(0);
    G1_CVT_WRITE(rb0, 0);
    LGKM_BAR();

#pragma unroll 1
    for (int i = 0; i < NS; i += 2) {
        // even step: read Bs[0]
        if (i + 2 < NS) G1_ISSUE_B(rb0, (i + 2) * 64);
        G1_COMPUTE(0);
        G1_ISSUE_A((i + 1) * 64);
        G1_CVT_WRITE(rb1, 1);
        LGKM_BAR();
        // odd step: read Bs[1]
        if (i + 3 < NS) G1_ISSUE_B(rb1, (i + 3) * 64);
        G1_COMPUTE(1);
        if (i + 2 < NS) {
            G1_ISSUE_A((i + 2) * 64);
            G1_CVT_WRITE(rb0, 0);
            LGKM_BAR();
        }
    }
#undef G1_ISSUE_B
#undef G1_CVT_WRITE
#undef G1_ISSUE_A
#undef G1_COMPUTE

    // epilogue: y = silu(gate)*up -> act bf16
#pragma unroll
    for (int m = 0; m < 2; ++m) {
#pragma unroll
        for (int f = 0; f < 4; ++f) {
            f32x4 g = acc[m][f], u = acc[m][f + 4];
#pragma unroll
            for (int j = 0; j < 4; ++j) {
                int lr = rowb - cb + m * 16 + kq * 4 + j + cb;  // = rowb + m*16 + kq*4 + j
                if (lr < Ne) {
                    float gv = g[j];
                    float y = gv / (1.f + __expf(-gv)) * u[j];
                    act[(size_t)(r0 + lr) * NINT + it * 64 + f * 16 + cl] = f2bf(y);
                }
            }
        }
    }
}

// ---------------- GEMM2 ----------------
// Block: 256 thr. Tile: 128 rows x 64 hid-cols. Same pipeline as gemm1.
__global__ __launch_bounds__(256, 4) void gemm2_kernel(
        const unsigned short* __restrict__ act, const float* __restrict__ w2,
        const int* __restrict__ meta, const int* __restrict__ rowTok,
        const float* __restrict__ rowW, float* __restrict__ out) {
    const int ch = blockIdx.x;      // 16 chunks of 128 rows
    const int ht = blockIdx.y;      // 32 tiles of 64 hid cols
    const int e  = blockIdx.z;
    const int r0 = meta[16 + e];
    const int Ne = meta[17 + e] - r0;
    const int cb = ch * 128;
    if (cb >= Ne) return;

    __shared__ __align__(16) short Bs[2][64][72];

    const int tid = threadIdx.x;
    const int lane = tid & 63, w = tid >> 6;
    const int cl = lane & 15, kq = lane >> 4;
    const int rowb = cb + w * 32;

    int ra0 = rowb + cl;      if (ra0 > Ne - 1) ra0 = Ne - 1;
    int ra1 = rowb + 16 + cl; if (ra1 > Ne - 1) ra1 = Ne - 1;
    const unsigned short* a0p = act + (size_t)(r0 + ra0) * NINT + kq * 8;
    const unsigned short* a1p = act + (size_t)(r0 + ra1) * NINT + kq * 8;

    const int tr = tid >> 2;                 // LDS row 0..63
    const int th = (tid & 3) * 16;           // k-quarter
    const float* wrow = w2 + ((size_t)e * HID + (size_t)ht * 64 + tr) * NINT + th;

    f32x4 acc[2][4];
#pragma unroll
    for (int m = 0; m < 2; ++m)
#pragma unroll
        for (int f = 0; f < 4; ++f) acc[m][f] = (f32x4){0.f, 0.f, 0.f, 0.f};

    fl4 rb0[4], rb1[4];
    short8 aS[2][2];

#define G2_ISSUE_B(RB, K0) do { \
        _Pragma("unroll") for (int i_ = 0; i_ < 4; ++i_) \
            RB[i_] = *(const fl4*)(wrow + (K0) + i_ * 4); \
    } while (0)

#define G2_CVT_WRITE(RB, BUF) do { \
        _Pragma("unroll") for (int i_ = 0; i_ < 2; ++i_) { \
            union { short8 s; unsigned int u[4]; } vv_; \
            vv_.u[0] = pk2(RB[2*i_][0], RB[2*i_][1]); \
            vv_.u[1] = pk2(RB[2*i_][2], RB[2*i_][3]); \
            vv_.u[2] = pk2(RB[2*i_+1][0], RB[2*i_+1][1]); \
            vv_.u[3] = pk2(RB[2*i_+1][2], RB[2*i_+1][3]); \
            *(short8*)&Bs[BUF][tr][th + i_ * 8] = vv_.s; \
        } \
    } while (0)

#define G2_ISSUE_A(K0) do { \
        aS[0][0] = *(const short8*)(a0p + (K0)); \
        aS[0][1] = *(const short8*)(a0p + (K0) + 32); \
        aS[1][0] = *(const short8*)(a1p + (K0)); \
        aS[1][1] = *(const short8*)(a1p + (K0) + 32); \
    } while (0)

#define G2_COMPUTE(BUF) do { \
        _Pragma("unroll") for (int h_ = 0; h_ < 2; ++h_) { \
            _Pragma("unroll") for (int f_ = 0; f_ < 4; ++f_) { \
                short8 b_ = *(const short8*)&Bs[BUF][f_ * 16 + cl][h_ * 32 + kq * 8]; \
                acc[0][f_] = __builtin_amdgcn_mfma_f32_16x16x32_bf16(aS[0][h_], b_, acc[0][f_], 0, 0, 0); \
                acc[1][f_] = __builtin_amdgcn_mfma_f32_16x16x32_bf16(aS[1][h_], b_, acc[1][f_], 0, 0, 0); \
            } \
        } \
    } while (0)

    const int NS = NINT / 64;   // 88 (even)
    G2_ISSUE_B(rb0, 0);
    G2_ISSUE_B(rb1, 64);
    G2_ISSUE_A(0);
    G2_CVT_WRITE(rb0, 0);
    LGKM_BAR();

#pragma unroll 1
    for (int i = 0; i < NS; i += 2) {
        if (i + 2 < NS) G2_ISSUE_B(rb0, (i + 2) * 64);
        G2_COMPUTE(0);
        G2_ISSUE_A((i + 1) * 64);
        G2_CVT_WRITE(rb1, 1);
        LGKM_BAR();
        if (i + 3 < NS) G2_ISSUE_B(rb1, (i + 3) * 64);
        G2_COMPUTE(1);
        if (i + 2 < NS) {
            G2_ISSUE_A((i + 2) * 64);
            G2_CVT_WRITE(rb0, 0);
            LGKM_BAR();
        }
    }
#undef G2_ISSUE_B
#undef G2_CVT_WRITE
#undef G2_ISSUE_A
#undef G2_COMPUTE

#pragma unroll
    for (int m = 0; m < 2; ++m) {
#pragma unroll
        for (int j = 0; j < 4; ++j) {
            int lr = rowb + m * 16 + kq * 4 + j;
            if (lr < Ne) {
                int slot = r0 + lr;
                int tok = rowTok[slot];
                float sw = rowW[slot];
#pragma unroll
                for (int f = 0; f < 4; ++f)
                    atomicAdd(&out[(size_t)tok * HID + ht * 64 + f * 16 + cl], acc[m][f][j] * sw);
            }
        }
    }
}

extern "C" void kernel_launch(void* const* d_in, const int* in_sizes, int n_in,
                              void* d_out, int out_size, void* d_ws, size_t ws_size,
                              hipStream_t stream) {
    const float* x      = (const float*)d_in[0];
    const float* logits = (const float*)d_in[1];
    const float* w1     = (const float*)d_in[2];
    const float* w3     = (const float*)d_in[3];
    const float* w2     = (const float*)d_in[4];
    float* out = (float*)d_out;

    char* ws = (char*)d_ws;
    int*   meta   = (int*)ws;                       // 32 ints
    int*   rowTok = (int*)(ws + 512);               // 4096 ints
    float* rowW   = (float*)(ws + 512 + 16384);     // 4096 floats
    unsigned short* xg  = (unsigned short*)(ws + (1u << 20));   // 16 MB
    unsigned short* act = (unsigned short*)(ws + (18u << 20));  // 44 MB

    zero_kernel<<<4096, 256, 0, stream>>>(out, meta);
    route_count<<<8, 256, 0, stream>>>(logits, meta);
    scan_kernel<<<1, 1, 0, stream>>>(meta);
    route_assign<<<8, 256, 0, stream>>>(logits, meta, rowTok, rowW);
    gather_x<<<4096, 256, 0, stream>>>(x, rowTok, xg);
    gemm1_kernel<<<dim3(16, 88, 8), 256, 0, stream>>>(xg, w1, w3, meta, act);
    gemm2_kernel<<<dim3(16, 32, 8), 256, 0, stream>>>(act, w2, meta, rowTok, rowW, out);
}

// Round 5
// 864.717 us; speedup vs baseline: 4.2695x; 4.2695x over previous
//
#include <hip/hip_runtime.h>
#include <hip/hip_bf16.h>
#include <cstdint>
#include <cstddef>

#define NTOK 2048
#define HID  2048
#define NINT 5632
#define NEXP 8

typedef __attribute__((ext_vector_type(8))) short short8;
typedef __attribute__((ext_vector_type(4))) float f32x4;
typedef __attribute__((ext_vector_type(4))) int   int4v;
typedef __attribute__((ext_vector_type(2))) int   int2v;
typedef __attribute__((ext_vector_type(4))) float fl4;

__device__ __forceinline__ unsigned short f2bf(float f) {
    union { float f; unsigned int u; } v; v.f = f;
    unsigned int r = (v.u + 0x7fffu + ((v.u >> 16) & 1u)) >> 16;
    return (unsigned short)r;
}

// pack 2 floats -> 2 bf16 (v_cvt_pk_bf16_f32, RNE)
__device__ __forceinline__ unsigned int pk2(float x, float y) {
    __hip_bfloat162 h = __float22bfloat162_rn(make_float2(x, y));
    union { __hip_bfloat162 h; unsigned int u; } c; c.h = h;
    return c.u;
}

// meta layout (ints): [0..7]=cnt, [8..15]=cursor, [16..24]=offs
__global__ void zero_kernel(float* __restrict__ out, int* __restrict__ meta) {
    int idx = blockIdx.x * blockDim.x + threadIdx.x;
    fl4 z = {0.f, 0.f, 0.f, 0.f};
    ((fl4*)out)[idx] = z;
    if (blockIdx.x == 0 && threadIdx.x < 16) meta[threadIdx.x] = 0;
}

__device__ __forceinline__ void top2_route(const float* __restrict__ lg, int t,
                                           int& e0, int& e1, float& w0, float& w1) {
    float l[NEXP];
#pragma unroll
    for (int e = 0; e < NEXP; ++e) l[e] = lg[t * NEXP + e];
    e0 = 0; float b0l = l[0];
#pragma unroll
    for (int e = 1; e < NEXP; ++e) if (l[e] > b0l) { b0l = l[e]; e0 = e; }
    e1 = (e0 == 0) ? 1 : 0; float b1l = l[e1];
#pragma unroll
    for (int e = 0; e < NEXP; ++e) {
        if (e == e0) continue;
        if (l[e] > b1l) { b1l = l[e]; e1 = e; }
    }
    float m = b0l;
    float p0 = __expf(b0l - m), p1 = __expf(b1l - m);
    float inv = 1.f / (p0 + p1);
    w0 = p0 * inv; w1 = p1 * inv;
}

__global__ void route_count(const float* __restrict__ logits, int* __restrict__ meta) {
    int t = blockIdx.x * blockDim.x + threadIdx.x;
    int e0, e1; float w0, w1;
    top2_route(logits, t, e0, e1, w0, w1);
    atomicAdd(&meta[e0], 1);
    atomicAdd(&meta[e1], 1);
}

__global__ void scan_kernel(int* __restrict__ meta) {
    if (threadIdx.x == 0 && blockIdx.x == 0) {
        int s = 0;
#pragma unroll
        for (int e = 0; e < NEXP; ++e) { meta[16 + e] = s; s += meta[e]; }
        meta[16 + NEXP] = s;
    }
}

__global__ void route_assign(const float* __restrict__ logits, int* __restrict__ meta,
                             int* __restrict__ rowTok, float* __restrict__ rowW) {
    int t = blockIdx.x * blockDim.x + threadIdx.x;
    int e0, e1; float w0, w1;
    top2_route(logits, t, e0, e1, w0, w1);
    int p0 = atomicAdd(&meta[8 + e0], 1);
    int s0 = meta[16 + e0] + p0;
    rowTok[s0] = t; rowW[s0] = w0;
    int p1 = atomicAdd(&meta[8 + e1], 1);
    int s1 = meta[16 + e1] + p1;
    rowTok[s1] = t; rowW[s1] = w1;
}

__global__ void gather_x(const float* __restrict__ x, const int* __restrict__ rowTok,
                         unsigned short* __restrict__ xg) {
    int slot = blockIdx.x;
    int tok = rowTok[slot];
    int c = threadIdx.x;
    const fl4* src = (const fl4*)(x + (size_t)tok * HID);
    fl4 a = src[c * 2], b = src[c * 2 + 1];
    short8 v;
    v[0] = (short)f2bf(a[0]); v[1] = (short)f2bf(a[1]); v[2] = (short)f2bf(a[2]); v[3] = (short)f2bf(a[3]);
    v[4] = (short)f2bf(b[0]); v[5] = (short)f2bf(b[1]); v[6] = (short)f2bf(b[2]); v[7] = (short)f2bf(b[3]);
    *(short8*)(xg + (size_t)slot * HID + c * 8) = v;
}

// ---------------- GEMM1 ----------------
// Tile 256 rows x (64 gate + 64 up) cols, BK=32, double-buffered LDS.
// K-loop order: issue loads(i+1) -> MFMA(i) -> sync -> cvt+write(i+1) -> sync.
// Loads stay in flight during the MFMA phase; single stage-reg set (no spill).
__global__ __launch_bounds__(512, 4) void gemm1_kernel(
        const unsigned short* __restrict__ xg,
        const float* __restrict__ w1, const float* __restrict__ w3,
        const int* __restrict__ meta, unsigned short* __restrict__ act) {
    const int it = blockIdx.x;      // 88 tiles of 64 inter cols
    const int e  = blockIdx.y;      // 8
    const int ch = blockIdx.z;      // 8 chunks of 256 rows
    const int r0 = meta[16 + e];
    const int Ne = meta[17 + e] - r0;
    const int cb = ch * 256;
    if (cb >= Ne) return;

    __shared__ __align__(16) short As[2][256][40];   // 40 KB
    __shared__ __align__(16) short Bs[2][128][40];   // 20 KB

    const int tid = threadIdx.x;
    const int lane = tid & 63, w = tid >> 6;
    const int cl = lane & 15, kq = lane >> 4;

    // A staging: row ar (0..255), 16-short half ah
    const int ar = tid >> 1, ah = (tid & 1) * 16;
    int asrow = cb + ar; if (asrow > Ne - 1) asrow = Ne - 1;
    const unsigned short* aptr = xg + (size_t)(r0 + asrow) * HID + ah;
    // B staging: row tr (0..127 = 64 gate + 64 up), 8-elem quarter tq
    const int tr = tid >> 2, tq = (tid & 3) * 8;
    const float* wsrc = ((tr < 64) ? w1 : w3)
        + ((size_t)e * NINT + (size_t)it * 64 + (tr & 63)) * HID + tq;

    f32x4 acc[2][8];
#pragma unroll
    for (int m = 0; m < 2; ++m)
#pragma unroll
        for (int f = 0; f < 8; ++f) acc[m][f] = (f32x4){0.f, 0.f, 0.f, 0.f};

    int4v ra[2];
    fl4   rbf[2];

#define G1_LOAD(K0) do { \
        ra[0] = *(const int4v*)(aptr + (K0)); \
        ra[1] = *(const int4v*)(aptr + (K0) + 8); \
        rbf[0] = *(const fl4*)(wsrc + (K0)); \
        rbf[1] = *(const fl4*)(wsrc + (K0) + 4); \
    } while (0)

#define G1_CVTWRITE(BUF) do { \
        *(int4v*)&As[BUF][ar][ah]     = ra[0]; \
        *(int4v*)&As[BUF][ar][ah + 8] = ra[1]; \
        union { short8 s; unsigned int u[4]; } vv_; \
        vv_.u[0] = pk2(rbf[0][0], rbf[0][1]); \
        vv_.u[1] = pk2(rbf[0][2], rbf[0][3]); \
        vv_.u[2] = pk2(rbf[1][0], rbf[1][1]); \
        vv_.u[3] = pk2(rbf[1][2], rbf[1][3]); \
        *(short8*)&Bs[BUF][tr][tq] = vv_.s; \
    } while (0)

#define G1_COMPUTE(BUF) do { \
        short8 a0_ = *(const short8*)&As[BUF][w * 32 + cl][kq * 8]; \
        short8 a1_ = *(const short8*)&As[BUF][w * 32 + 16 + cl][kq * 8]; \
        _Pragma("unroll") for (int f_ = 0; f_ < 8; ++f_) { \
            short8 b_ = *(const short8*)&Bs[BUF][f_ * 16 + cl][kq * 8]; \
            acc[0][f_] = __builtin_amdgcn_mfma_f32_16x16x32_bf16(a0_, b_, acc[0][f_], 0, 0, 0); \
            acc[1][f_] = __builtin_amdgcn_mfma_f32_16x16x32_bf16(a1_, b_, acc[1][f_], 0, 0, 0); \
        } \
    } while (0)

    const int NS = HID / 32;   // 64
    G1_LOAD(0);
    G1_CVTWRITE(0);
    __syncthreads();

#pragma unroll 1
    for (int i = 0; i < NS; ++i) {
        const int p = i & 1;
        if (i + 1 < NS) G1_LOAD((i + 1) * 32);
        __builtin_amdgcn_sched_barrier(0);
        G1_COMPUTE(p);
        __builtin_amdgcn_sched_barrier(0);
        __syncthreads();
        if (i + 1 < NS) G1_CVTWRITE(p ^ 1);
        __syncthreads();
    }
#undef G1_LOAD
#undef G1_CVTWRITE
#undef G1_COMPUTE

    // epilogue: y = silu(gate)*up -> act bf16
    const int rowb = cb + w * 32;
#pragma unroll
    for (int m = 0; m < 2; ++m) {
#pragma unroll
        for (int f = 0; f < 4; ++f) {
            f32x4 g = acc[m][f], u = acc[m][f + 4];
#pragma unroll
            for (int j = 0; j < 4; ++j) {
                int lr = rowb + m * 16 + kq * 4 + j;
                if (lr - cb < 256 && lr < Ne) {
                    float gv = g[j];
                    float y = gv / (1.f + __expf(-gv)) * u[j];
                    act[(size_t)(r0 + lr) * NINT + it * 64 + f * 16 + cl] = f2bf(y);
                }
            }
        }
    }
}

// ---------------- GEMM2 ----------------
// Tile 256 rows x 64 hid cols, BK=32, same pipeline.
__global__ __launch_bounds__(512, 4) void gemm2_kernel(
        const unsigned short* __restrict__ act, const float* __restrict__ w2,
        const int* __restrict__ meta, const int* __restrict__ rowTok,
        const float* __restrict__ rowW, float* __restrict__ out) {
    const int ht = blockIdx.x;      // 32 tiles of 64 hid cols
    const int e  = blockIdx.y;
    const int ch = blockIdx.z;
    const int r0 = meta[16 + e];
    const int Ne = meta[17 + e] - r0;
    const int cb = ch * 256;
    if (cb >= Ne) return;

    __shared__ __align__(16) short As[2][256][40];
    __shared__ __align__(16) short Bs[2][64][40];

    const int tid = threadIdx.x;
    const int lane = tid & 63, w = tid >> 6;
    const int cl = lane & 15, kq = lane >> 4;

    const int ar = tid >> 1, ah = (tid & 1) * 16;
    int asrow = cb + ar; if (asrow > Ne - 1) asrow = Ne - 1;
    const unsigned short* aptr = act + (size_t)(r0 + asrow) * NINT + ah;
    // B staging: row tr (0..63), 4-elem eighth tq
    const int tr = tid >> 3, tq = (tid & 7) * 4;
    const float* wsrc = w2 + ((size_t)e * HID + (size_t)ht * 64 + tr) * NINT + tq;

    f32x4 acc[2][4];
#pragma unroll
    for (int m = 0; m < 2; ++m)
#pragma unroll
        for (int f = 0; f < 4; ++f) acc[m][f] = (f32x4){0.f, 0.f, 0.f, 0.f};

    int4v ra[2];
    fl4   rbf;

#define G2_LOAD(K0) do { \
        ra[0] = *(const int4v*)(aptr + (K0)); \
        ra[1] = *(const int4v*)(aptr + (K0) + 8); \
        rbf = *(const fl4*)(wsrc + (K0)); \
    } while (0)

#define G2_CVTWRITE(BUF) do { \
        *(int4v*)&As[BUF][ar][ah]     = ra[0]; \
        *(int4v*)&As[BUF][ar][ah + 8] = ra[1]; \
        union { int2v s; unsigned int u[2]; } vv_; \
        vv_.u[0] = pk2(rbf[0], rbf[1]); \
        vv_.u[1] = pk2(rbf[2], rbf[3]); \
        *(int2v*)&Bs[BUF][tr][tq] = vv_.s; \
    } while (0)

#define G2_COMPUTE(BUF) do { \
        short8 a0_ = *(const short8*)&As[BUF][w * 32 + cl][kq * 8]; \
        short8 a1_ = *(const short8*)&As[BUF][w * 32 + 16 + cl][kq * 8]; \
        _Pragma("unroll") for (int f_ = 0; f_ < 4; ++f_) { \
            short8 b_ = *(const short8*)&Bs[BUF][f_ * 16 + cl][kq * 8]; \
            acc[0][f_] = __builtin_amdgcn_mfma_f32_16x16x32_bf16(a0_, b_, acc[0][f_], 0, 0, 0); \
            acc[1][f_] = __builtin_amdgcn_mfma_f32_16x16x32_bf16(a1_, b_, acc[1][f_], 0, 0, 0); \
        } \
    } while (0)

    const int NS = NINT / 32;   // 176
    G2_LOAD(0);
    G2_CVTWRITE(0);
    __syncthreads();

#pragma unroll 1
    for (int i = 0; i < NS; ++i) {
        const int p = i & 1;
        if (i + 1 < NS) G2_LOAD((i + 1) * 32);
        __builtin_amdgcn_sched_barrier(0);
        G2_COMPUTE(p);
        __builtin_amdgcn_sched_barrier(0);
        __syncthreads();
        if (i + 1 < NS) G2_CVTWRITE(p ^ 1);
        __syncthreads();
    }
#undef G2_LOAD
#undef G2_CVTWRITE
#undef G2_COMPUTE

    const int rowb = cb + w * 32;
#pragma unroll
    for (int m = 0; m < 2; ++m) {
#pragma unroll
        for (int j = 0; j < 4; ++j) {
            int lr = rowb + m * 16 + kq * 4 + j;
            if (lr < Ne) {
                int slot = r0 + lr;
                int tok = rowTok[slot];
                float sw = rowW[slot];
#pragma unroll
                for (int f = 0; f < 4; ++f)
                    atomicAdd(&out[(size_t)tok * HID + ht * 64 + f * 16 + cl], acc[m][f][j] * sw);
            }
        }
    }
}

extern "C" void kernel_launch(void* const* d_in, const int* in_sizes, int n_in,
                              void* d_out, int out_size, void* d_ws, size_t ws_size,
                              hipStream_t stream) {
    const float* x      = (const float*)d_in[0];
    const float* logits = (const float*)d_in[1];
    const float* w1     = (const float*)d_in[2];
    const float* w3     = (const float*)d_in[3];
    const float* w2     = (const float*)d_in[4];
    float* out = (float*)d_out;

    char* ws = (char*)d_ws;
    int*   meta   = (int*)ws;                       // 32 ints
    int*   rowTok = (int*)(ws + 512);               // 4096 ints
    float* rowW   = (float*)(ws + 512 + 16384);     // 4096 floats
    unsigned short* xg  = (unsigned short*)(ws + (1u << 20));   // 16 MB
    unsigned short* act = (unsigned short*)(ws + (18u << 20));  // 44 MB

    zero_kernel<<<4096, 256, 0, stream>>>(out, meta);
    route_count<<<8, 256, 0, stream>>>(logits, meta);
    scan_kernel<<<1, 1, 0, stream>>>(meta);
    route_assign<<<8, 256, 0, stream>>>(logits, meta, rowTok, rowW);
    gather_x<<<4096, 256, 0, stream>>>(x, rowTok, xg);
    gemm1_kernel<<<dim3(88, 8, 8), 512, 0, stream>>>(xg, w1, w3, meta, act);
    gemm2_kernel<<<dim3(32, 8, 8), 512, 0, stream>>>(act, w2, meta, rowTok, rowW, out);
}